// Round 16
// baseline (151.952 us; speedup 1.0000x reference)
//
#include <hip/hip_runtime.h>

typedef unsigned short bfu;
typedef __attribute__((ext_vector_type(8))) short short8;
typedef __attribute__((ext_vector_type(4))) float f32x4;

__device__ __forceinline__ float bf2f(bfu u){
  union { unsigned int i; float f; } v; v.i = ((unsigned int)u) << 16; return v.f;
}
__device__ __forceinline__ bfu f2bf(float f){
  union { float f; unsigned int i; } v; v.f = f;
  unsigned int r = (v.i + 0x7FFFu + ((v.i >> 16) & 1u)) >> 16;
  return (bfu)r;
}
__device__ __forceinline__ float fexp2(float x){ return __builtin_amdgcn_exp2f(x); }
__device__ __forceinline__ float flog2(float x){ return __builtin_amdgcn_logf(x); }
__device__ __forceinline__ float softplusf(float x){
  float t = fexp2(-fabsf(x) * 1.44269504088896f);
  return fmaxf(x, 0.f) + 0.69314718055995f * flog2(1.f + t);
}
__device__ __forceinline__ void gload16(const bfu* g, bfu* l){
  __builtin_amdgcn_global_load_lds((const __attribute__((address_space(1))) unsigned int*)g,
                                   (__attribute__((address_space(3))) unsigned int*)l, 16, 0, 0);
}

// ---------------- fused conversion kernel (LDS-tiled coalesced transposes) ----------------
__global__ __launch_bounds__(256) void cvt_all_kernel(const float* __restrict__ x, bfu* __restrict__ x_bf,
                                                      const float* __restrict__ W_in, const float* __restrict__ W_out,
                                                      const float* __restrict__ W_x,
                                                      bfu* __restrict__ WinT, bfu* __restrict__ WoutT,
                                                      float* __restrict__ WxT){
  __shared__ float T[32][33];
  const int bid = blockIdx.x;
  const int tid = threadIdx.x;
  if (bid < 8192){
    int g = bid * 256 + tid;
    float4 v = ((const float4*)x)[g];
    ushort4 o;
    o.x = f2bf(v.x); o.y = f2bf(v.y); o.z = f2bf(v.z); o.w = f2bf(v.w);
    ((ushort4*)x_bf)[g] = o;
    return;
  }
  const int lr = tid >> 3;
  const int lc = tid & 7;
  if (bid < 8960){
    int ti = bid - 8192;
    int r0 = (ti & 15) * 32, c0 = (ti >> 4) * 32;
    float4 v = *(const float4*)(W_in + (size_t)(r0 + lr) * 1536 + c0 + lc * 4);
    T[lr][lc * 4 + 0] = v.x; T[lr][lc * 4 + 1] = v.y;
    T[lr][lc * 4 + 2] = v.z; T[lr][lc * 4 + 3] = v.w;
    __syncthreads();
    ushort4 o;
    o.x = f2bf(T[lc * 4 + 0][lr]); o.y = f2bf(T[lc * 4 + 1][lr]);
    o.z = f2bf(T[lc * 4 + 2][lr]); o.w = f2bf(T[lc * 4 + 3][lr]);
    *(ushort4*)(WinT + (size_t)(c0 + lr) * 512 + r0 + lc * 4) = o;
  } else if (bid < 9344){
    int ti = bid - 8960;
    int r0 = (ti % 24) * 32, c0 = (ti / 24) * 32;
    float4 v = *(const float4*)(W_out + (size_t)(r0 + lr) * 512 + c0 + lc * 4);
    T[lr][lc * 4 + 0] = v.x; T[lr][lc * 4 + 1] = v.y;
    T[lr][lc * 4 + 2] = v.z; T[lr][lc * 4 + 3] = v.w;
    __syncthreads();
    ushort4 o;
    o.x = f2bf(T[lc * 4 + 0][lr]); o.y = f2bf(T[lc * 4 + 1][lr]);
    o.z = f2bf(T[lc * 4 + 2][lr]); o.w = f2bf(T[lc * 4 + 3][lr]);
    *(ushort4*)(WoutT + (size_t)(c0 + lr) * 768 + r0 + lc * 4) = o;
  } else {
    int h = (bid - 9344) * 256 + tid;
    int n = h / 768, k = h % 768;
    WxT[h] = W_x[(size_t)k * 8 + n];
  }
}

// ---------------- GEMM1: 256x256 tile, BK=64, derived 8-phase schedule ----------------
// 8 waves (2M x 4N), per-wave 128x64 (acc[8][4]).  LDS: A[2][256][64] + B[2][256][64]
// = 128 KB (1 block/CU).  Per K-tile: 4 quadrant phases, each {ds_read || 2 quarter
// gloads -> s_barrier -> lgkmcnt(0) -> setprio 16 MFMA -> barrier}.  vmcnt(4) before
// the 2nd barrier of phases 4/8.  Stage slots proven region-free (see derivation).
template<int EPI, int KK>
__global__ __launch_bounds__(512)
void gemm_8x(const bfu* __restrict__ Amat, const bfu* __restrict__ Bt,
             void* __restrict__ out0, void* __restrict__ out1,
             int NBN, int N)
{
  constexpr int NT = KK / 64;
  __shared__ bfu LDS[4 * 16384];   // [A buf0][A buf1][B buf0][B buf1], each 256x64
  const int tid  = threadIdx.x;
  const int lane = tid & 63;
  const int w    = tid >> 6;
  const int wr   = w >> 2;         // 0..1  (M half)
  const int wc   = w & 3;          // 0..3  (N quarter)

  const int cpx = gridDim.x >> 3;
  const int id  = blockIdx.x;
  const int nid = (id & 7) * cpx + (id >> 3);
  const int bn  = nid % NBN;
  const int bm  = nid / NBN;

  // staging: quarter = 64 rows x 64 cols (8KB = 1 gload x 512 thr x 16B)
  const int srow = tid >> 3;
  const int scol = ((tid & 7) ^ (srow & 7)) * 8;   // pre-swizzled source col (T2)
  const bfu* gA = Amat + ((size_t)(bm * 256 + srow)) * KK + scol;
  const bfu* gB = Bt   + ((size_t)(bn * 256 + srow)) * KK + scol;

  auto stA = [&](int t, int q){
    bfu* dst = (bfu*)LDS + (t & 1) * 16384 + q * 4096 + tid * 8;
    gload16(gA + (size_t)(q * 64) * KK + t * 64, dst);
  };
  auto stB = [&](int t, int q){
    bfu* dst = (bfu*)LDS + 32768 + (t & 1) * 16384 + q * 4096 + tid * 8;
    gload16(gB + (size_t)(q * 64) * KK + t * 64, dst);
  };

  #define RDA(dst, Abase, m0)                                          \
    _Pragma("unroll") for (int mi = 0; mi < 4; mi++)                   \
    _Pragma("unroll") for (int kk = 0; kk < 2; kk++){                  \
      int r_ = wr * 128 + ((m0) + mi) * 16 + (lane & 15);              \
      int s_ = ((kk * 4 + (lane >> 4)) ^ (lane & 7)) * 8;              \
      dst[mi][kk] = *(const short8*)&Abase[r_ * 64 + s_];              \
    }
  #define RDB(dst, Bbase, n0)                                          \
    _Pragma("unroll") for (int ni = 0; ni < 2; ni++)                   \
    _Pragma("unroll") for (int kk = 0; kk < 2; kk++){                  \
      int r_ = wc * 64 + ((n0) + ni) * 16 + (lane & 15);               \
      int s_ = ((kk * 4 + (lane >> 4)) ^ (lane & 7)) * 8;              \
      dst[ni][kk] = *(const short8*)&Bbase[r_ * 64 + s_];              \
    }
  #define MM16(av, bv, m0, n0)                                         \
    _Pragma("unroll") for (int mi = 0; mi < 4; mi++)                   \
    _Pragma("unroll") for (int ni = 0; ni < 2; ni++)                   \
    _Pragma("unroll") for (int kk = 0; kk < 2; kk++)                   \
      acc[(m0) + mi][(n0) + ni] = __builtin_amdgcn_mfma_f32_16x16x32_bf16( \
          av[mi][kk], bv[ni][kk], acc[(m0) + mi][(n0) + ni], 0, 0, 0);
  #define PH_SYNC()                                                    \
    __builtin_amdgcn_s_barrier();                                      \
    asm volatile("s_waitcnt lgkmcnt(0)" ::: "memory");                 \
    __builtin_amdgcn_sched_barrier(0);

  f32x4 acc[8][4];
  #pragma unroll
  for (int i = 0; i < 8; i++)
    #pragma unroll
    for (int j = 0; j < 4; j++)
      #pragma unroll
      for (int r = 0; r < 4; r++) acc[i][j][r] = 0.f;

  // prologue: mimic steady-state stage stream (12 gloads), tile0 fully landed
  stA(0, 1); stA(0, 3);
  stB(0, 0); stB(0, 1);
  stB(0, 2); stB(0, 3);
  stA(0, 0); stA(0, 2);
  stA(1, 1); stA(1, 3);
  stB(1, 0); stB(1, 1);
  asm volatile("s_waitcnt vmcnt(4)" ::: "memory");
  __builtin_amdgcn_s_barrier();

  for (int t = 0; t < NT; t += 2){
    const bfu* Ab0 = (const bfu*)LDS + (t & 1) * 16384;
    const bfu* Bb0 = (const bfu*)LDS + 32768 + (t & 1) * 16384;
    const bfu* Ab1 = (const bfu*)LDS + ((t + 1) & 1) * 16384;
    const bfu* Bb1 = (const bfu*)LDS + 32768 + ((t + 1) & 1) * 16384;
    short8 a[4][2], a2[4][2], b[2][2];

    // ---- tile t (phases 1-4) ----
    RDA(a, Ab0, 0); RDB(b, Bb0, 0);
    stB(t + 1, 2); stB(t + 1, 3);                        // P1 stage: B1(t+1)
    PH_SYNC();
    __builtin_amdgcn_s_setprio(1); MM16(a, b, 0, 0); __builtin_amdgcn_s_setprio(0);
    __builtin_amdgcn_s_barrier();

    RDA(a2, Ab0, 4);
    stA(t + 1, 0); stA(t + 1, 2);                        // P2 stage: Aq0,2(t+1)
    PH_SYNC();
    __builtin_amdgcn_s_setprio(1); MM16(a2, b, 4, 0); __builtin_amdgcn_s_setprio(0);
    __builtin_amdgcn_s_barrier();

    RDB(b, Bb0, 2);
    if (t + 2 < NT){ stA(t + 2, 1); stA(t + 2, 3); }     // P3 stage: Aq1,3(t+2)
    PH_SYNC();
    __builtin_amdgcn_s_setprio(1); MM16(a2, b, 4, 2); __builtin_amdgcn_s_setprio(0);
    __builtin_amdgcn_s_barrier();

    RDA(a, Ab0, 0);
    if (t + 2 < NT){ stB(t + 2, 0); stB(t + 2, 1); }     // P4 stage: B0(t+2)
    PH_SYNC();
    __builtin_amdgcn_s_setprio(1); MM16(a, b, 0, 2); __builtin_amdgcn_s_setprio(0);
    if (t + 2 < NT) asm volatile("s_waitcnt vmcnt(4)" ::: "memory");
    else            asm volatile("s_waitcnt vmcnt(0)" ::: "memory");
    __builtin_amdgcn_s_barrier();

    // ---- tile t+1 (phases 5-8) ----
    RDA(a, Ab1, 0); RDB(b, Bb1, 0);
    if (t + 2 < NT){ stB(t + 2, 2); stB(t + 2, 3); }     // P5 stage: B1(t+2)
    PH_SYNC();
    __builtin_amdgcn_s_setprio(1); MM16(a, b, 0, 0); __builtin_amdgcn_s_setprio(0);
    __builtin_amdgcn_s_barrier();

    RDA(a2, Ab1, 4);
    if (t + 2 < NT){ stA(t + 2, 0); stA(t + 2, 2); }     // P6 stage: Aq0,2(t+2)
    PH_SYNC();
    __builtin_amdgcn_s_setprio(1); MM16(a2, b, 4, 0); __builtin_amdgcn_s_setprio(0);
    __builtin_amdgcn_s_barrier();

    RDB(b, Bb1, 2);
    if (t + 3 < NT){ stA(t + 3, 1); stA(t + 3, 3); }     // P7 stage: Aq1,3(t+3)
    PH_SYNC();
    __builtin_amdgcn_s_setprio(1); MM16(a2, b, 4, 2); __builtin_amdgcn_s_setprio(0);
    __builtin_amdgcn_s_barrier();

    RDA(a, Ab1, 0);
    if (t + 3 < NT){ stB(t + 3, 0); stB(t + 3, 1); }     // P8 stage: B0(t+3)
    PH_SYNC();
    __builtin_amdgcn_s_setprio(1); MM16(a, b, 0, 2); __builtin_amdgcn_s_setprio(0);
    asm volatile("s_waitcnt vmcnt(4)" ::: "memory");
    __builtin_amdgcn_s_barrier();
  }
  #undef RDA
  #undef RDB
  #undef MM16
  #undef PH_SYNC

  #pragma unroll
  for (int m = 0; m < 8; m++){
    #pragma unroll
    for (int n = 0; n < 4; n++){
      const int row0 = bm * 256 + wr * 128 + m * 16 + (lane >> 4) * 4;
      const int col  = bn * 256 + wc * 64 + n * 16 + (lane & 15);
      #pragma unroll
      for (int r = 0; r < 4; r++){
        float v = acc[m][n][r];
        int row = row0 + r;
        if (EPI == 0){
          float s = v / (1.f + __expf(-v));   // silu
          if (col < 768) ((bfu*)out0)[(size_t)row * 768 + col]         = f2bf(s);
          else           ((bfu*)out1)[(size_t)row * 768 + (col - 768)] = f2bf(s);
        } else {
          ((float*)out0)[(size_t)row * N + col] = v;
        }
      }
    }
  }
}

// ---------------- GEMM2 (r11-proven): BM x 128, BK=64, single-buffer ----------------
template<int EPI, int BM, int KK>
__global__ __launch_bounds__(BM * 2)
void gemm_sb(const bfu* __restrict__ Amat, const bfu* __restrict__ Bt,
             void* __restrict__ out0, void* __restrict__ out1,
             int NBN, int N)
{
  constexpr int BN = 128;
  constexpr int THREADS = BM * 2;
  constexpr int RPI = THREADS / 8;
  __shared__ bfu As[BM * 64];
  __shared__ bfu Bs[BN * 64];
  const int tid  = threadIdx.x;
  const int lane = tid & 63;
  const int w    = tid >> 6;
  const int wr   = w >> 1, wc = w & 1;

  const int cpx = gridDim.x >> 3;
  const int id  = blockIdx.x;
  const int nid = (id & 7) * cpx + (id >> 3);
  const int bn  = nid % NBN;
  const int bm  = nid / NBN;

  const int srow = tid >> 3;
  const int scol = ((tid & 7) ^ (srow & 7)) * 8;
  const bfu* gA = Amat + ((size_t)(bm * BM + srow)) * KK + scol;
  const bfu* gB = Bt   + ((size_t)(bn * BN + srow)) * KK + scol;
  bfu* lA = As + srow * 64 + (tid & 7) * 8;
  bfu* lB = Bs + srow * 64 + (tid & 7) * 8;

  f32x4 acc[4][4];
  #pragma unroll
  for (int i = 0; i < 4; i++)
    #pragma unroll
    for (int j = 0; j < 4; j++)
      #pragma unroll
      for (int r = 0; r < 4; r++) acc[i][j][r] = 0.f;

  for (int k0 = 0; k0 < KK; k0 += 64){
    #pragma unroll
    for (int i = 0; i < BM / RPI; i++)
      gload16(gA + (size_t)(i * RPI) * KK + k0, lA + i * RPI * 64);
    #pragma unroll
    for (int j = 0; j < BN / RPI; j++)
      gload16(gB + (size_t)(j * RPI) * KK + k0, lB + j * RPI * 64);
    __syncthreads();

    #pragma unroll
    for (int kk = 0; kk < 2; kk++){
      short8 a[4], b[4];
      const int sA = ((kk * 4 + (lane >> 4)) ^ (lane & 7)) * 8;
      #pragma unroll
      for (int m = 0; m < 4; m++){
        int r = wr * 64 + m * 16 + (lane & 15);
        a[m] = *(const short8*)&As[r * 64 + sA];
      }
      #pragma unroll
      for (int n = 0; n < 4; n++){
        int r = wc * 64 + n * 16 + (lane & 15);
        b[n] = *(const short8*)&Bs[r * 64 + sA];
      }
      #pragma unroll
      for (int m = 0; m < 4; m++)
        #pragma unroll
        for (int n = 0; n < 4; n++)
          acc[m][n] = __builtin_amdgcn_mfma_f32_16x16x32_bf16(a[m], b[n], acc[m][n], 0, 0, 0);
    }
    __syncthreads();
  }

  #pragma unroll
  for (int m = 0; m < 4; m++){
    #pragma unroll
    for (int n = 0; n < 4; n++){
      const int row0 = bm * BM + wr * 64 + m * 16 + (lane >> 4) * 4;
      const int col  = bn * BN + wc * 64 + n * 16 + (lane & 15);
      #pragma unroll
      for (int r = 0; r < 4; r++){
        float v = acc[m][n][r];
        int row = row0 + r;
        if (EPI == 0){
          float s = v / (1.f + __expf(-v));
          if (col < 768) ((bfu*)out0)[(size_t)row * 768 + col]         = f2bf(s);
          else           ((bfu*)out1)[(size_t)row * 768 + (col - 768)] = f2bf(s);
        } else {
          ((float*)out0)[(size_t)row * N + col] = v;
        }
      }
    }
  }
}

// ---------------- u = xssm @ W_x  (uses WxT [8][768], coalesced) ----------------
__global__ __launch_bounds__(256) void u_kernel(const bfu* __restrict__ xssm, const float* __restrict__ WxT,
                                                float* __restrict__ u){
  int wid = threadIdx.x >> 6, lane = threadIdx.x & 63;
  int row = blockIdx.x * 4 + wid;
  const bfu* xr = xssm + (size_t)row * 768;
  float acc[8];
  #pragma unroll
  for (int n = 0; n < 8; n++) acc[n] = 0.f;
  #pragma unroll
  for (int i = 0; i < 3; i++){
    int kb = i * 256 + lane * 4;
    ushort4 xq = *(const ushort4*)(xr + kb);
    float x0 = bf2f(xq.x), x1 = bf2f(xq.y), x2 = bf2f(xq.z), x3 = bf2f(xq.w);
    #pragma unroll
    for (int n = 0; n < 8; n++){
      float4 wv = *(const float4*)(WxT + (size_t)n * 768 + kb);
      acc[n] += x0 * wv.x + x1 * wv.y + x2 * wv.z + x3 * wv.w;
    }
  }
  #pragma unroll
  for (int n = 0; n < 8; n++){
    #pragma unroll
    for (int off = 32; off >= 1; off >>= 1) acc[n] += __shfl_xor(acc[n], off, 64);
  }
  if (lane == 0){
    float4 o0 = { acc[0], acc[1], acc[2], acc[3] };
    float4 o1 = { acc[4], acc[5], acc[6], acc[7] };
    *(float4*)(u + (size_t)row * 8)     = o0;
    *(float4*)(u + (size_t)row * 8 + 4) = o1;
  }
}

// ---------------- scan phase 1: 1 d/thread, u staged in LDS, delta inline ----------------
__global__ __launch_bounds__(256) void scan_phase1(const bfu* __restrict__ xssm, const float* __restrict__ u,
    const float* __restrict__ Wdt, const float* __restrict__ bdt, const float* __restrict__ A_log,
    float* __restrict__ Sws, float* __restrict__ Hws){
  __shared__ float uS[32][8];
  int tid = threadIdx.x;
  int bid = blockIdx.x;
  int b = bid / 192; int rem = bid % 192;
  int c = rem / 3;   int dblk = rem % 3;
  int d = dblk * 256 + tid;
  int r0 = b * 2048 + c * 32;
  uS[tid >> 3][tid & 7] = u[(size_t)(r0 + (tid >> 3)) * 8 + (tid & 7)];
  float Al2[8], H[8], Wr[8];
  float bd = bdt[d], S = 0.f;
  #pragma unroll
  for (int n = 0; n < 8; n++){
    Al2[n] = -__expf(A_log[(size_t)d * 8 + n]) * 1.4426950408889634f;
    Wr[n]  = Wdt[(size_t)n * 768 + d];
    H[n] = 0.f;
  }
  __syncthreads();
  size_t base = (size_t)r0 * 768 + d;
  #pragma unroll 8
  for (int i = 0; i < 32; i++){
    float4 u0 = *(const float4*)&uS[i][0];
    float4 u1 = *(const float4*)&uS[i][4];
    float xt = bf2f(xssm[base + (size_t)i * 768]);
    float dv = bd + u0.x * Wr[0] + u0.y * Wr[1] + u0.z * Wr[2] + u0.w * Wr[3]
                  + u1.x * Wr[4] + u1.y * Wr[5] + u1.z * Wr[6] + u1.w * Wr[7];
    float dt = softplusf(dv);
    float dx = dt * xt;
    S += dt;
    #pragma unroll
    for (int n = 0; n < 8; n++){
      float e = fexp2(dt * Al2[n]);
      H[n] = e * H[n] + dx;
    }
  }
  size_t o = (((size_t)b * 64 + c) * 768 + d) * 8;
  float4 h0 = { H[0], H[1], H[2], H[3] };
  float4 h1 = { H[4], H[5], H[6], H[7] };
  *(float4*)(Hws + o)     = h0;
  *(float4*)(Hws + o + 4) = h1;
  Sws[((size_t)b * 64 + c) * 768 + d] = S;
}

// ---------------- scan phase 2: combine chunks (P derived from S), batched prefetch ----------------
__global__ __launch_bounds__(256) void scan_phase2(const float* __restrict__ Sws, const float* __restrict__ Hws,
                                                   const float* __restrict__ A_log, float* __restrict__ Hin){
  int g = blockIdx.x * 256 + threadIdx.x;
  int within = g % 6144;
  int b = g / 6144;
  int d = within >> 3, n = within & 7;
  float Al2 = -__expf(A_log[(size_t)d * 8 + n]) * 1.4426950408889634f;
  size_t baseH = (size_t)b * 64 * 6144 + within;
  size_t baseS = (size_t)b * 64 * 768 + d;
  float hin = 0.f;
  float sv[16], hv[16];
  #pragma unroll
  for (int B = 0; B < 4; B++){
    #pragma unroll
    for (int i = 0; i < 16; i++){
      sv[i] = Sws[baseS + (size_t)(B * 16 + i) * 768];
      hv[i] = Hws[baseH + (size_t)(B * 16 + i) * 6144];
    }
    #pragma unroll
    for (int i = 0; i < 16; i++){
      size_t idx = baseH + (size_t)(B * 16 + i) * 6144;
      Hin[idx] = hin;
      hin = fexp2(sv[i] * Al2) * hin + hv[i];
    }
  }
}

// ---------------- scan phase 3: 1 d/thread, u staged in LDS, gate fused ----------------
__global__ __launch_bounds__(256) void scan_phase3(const bfu* __restrict__ xssm, const float* __restrict__ u,
    const float* __restrict__ Wdt, const float* __restrict__ bdt, const float* __restrict__ A_log,
    const float* __restrict__ Dp, const bfu* __restrict__ siluz, const float* __restrict__ Hin,
    bfu* __restrict__ yz){
  __shared__ float uS[32][8];
  int tid = threadIdx.x;
  int bid = blockIdx.x;
  int b = bid / 192; int rem = bid % 192;
  int c = rem / 3;   int dblk = rem % 3;
  int d = dblk * 256 + tid;
  int r0 = b * 2048 + c * 32;
  uS[tid >> 3][tid & 7] = u[(size_t)(r0 + (tid >> 3)) * 8 + (tid & 7)];
  float Al2[8], H[8], Wr[8];
  float bd = bdt[d], Dd = Dp[d];
  size_t o = (((size_t)b * 64 + c) * 768 + d) * 8;
  float4 h0 = *(const float4*)(Hin + o);
  float4 h1 = *(const float4*)(Hin + o + 4);
  H[0] = h0.x; H[1] = h0.y; H[2] = h0.z; H[3] = h0.w;
  H[4] = h1.x; H[5] = h1.y; H[6] = h1.z; H[7] = h1.w;
  #pragma unroll
  for (int n = 0; n < 8; n++){
    Al2[n] = -__expf(A_log[(size_t)d * 8 + n]) * 1.4426950408889634f;
    Wr[n]  = Wdt[(size_t)n * 768 + d];
  }
  __syncthreads();
  size_t base = (size_t)r0 * 768 + d;
  #pragma unroll 8
  for (int i = 0; i < 32; i++){
    float4 u0 = *(const float4*)&uS[i][0];
    float4 u1 = *(const float4*)&uS[i][4];
    float xt = bf2f(xssm[base + (size_t)i * 768]);
    float sz = bf2f(siluz[base + (size_t)i * 768]);
    float dv = bd + u0.x * Wr[0] + u0.y * Wr[1] + u0.z * Wr[2] + u0.w * Wr[3]
                  + u1.x * Wr[4] + u1.y * Wr[5] + u1.z * Wr[6] + u1.w * Wr[7];
    float dt = softplusf(dv);
    float dx = dt * xt;
    float y = Dd * xt;
    #pragma unroll
    for (int n = 0; n < 8; n++){
      float e = fexp2(dt * Al2[n]);
      H[n] = e * H[n] + dx;
      y += H[n];
    }
    yz[base + (size_t)i * 768] = f2bf(y * sz);
  }
}

extern "C" void kernel_launch(void* const* d_in, const int* in_sizes, int n_in,
                              void* d_out, int out_size, void* d_ws, size_t ws_size,
                              hipStream_t stream){
  const float* x     = (const float*)d_in[0];
  const float* W_in  = (const float*)d_in[1];
  const float* A_log = (const float*)d_in[2];
  const float* D_par = (const float*)d_in[3];
  const float* W_x   = (const float*)d_in[4];
  const float* W_dt  = (const float*)d_in[5];
  const float* b_dt  = (const float*)d_in[6];
  const float* W_out = (const float*)d_in[7];
  float* out = (float*)d_out;
  (void)in_sizes; (void)n_in; (void)out_size; (void)ws_size;

  char* base = (char*)d_ws;
  size_t off = 0;
  auto alloc = [&](size_t bytes)->char*{
    char* p = base + off; off += (bytes + 255) & ~(size_t)255; return p;
  };
  bfu*   x_bf  = (bfu*)  alloc((size_t)16384 * 512 * 2);
  bfu*   WinT  = (bfu*)  alloc((size_t)1536 * 512 * 2);
  bfu*   WoutT = (bfu*)  alloc((size_t)512 * 768 * 2);
  float* WxT   = (float*)alloc((size_t)8 * 768 * 4);
  bfu*   xssm  = (bfu*)  alloc((size_t)16384 * 768 * 2);
  bfu*   siluz = (bfu*)  alloc((size_t)16384 * 768 * 2);
  float* u     = (float*)alloc((size_t)16384 * 8 * 4);
  float* Sws   = (float*)alloc((size_t)8 * 64 * 768 * 4);
  float* Hws   = (float*)alloc((size_t)8 * 64 * 768 * 8 * 4);
  float* Hin   = (float*)alloc((size_t)8 * 64 * 768 * 8 * 4);
  bfu*   yz    = (bfu*)  alloc((size_t)16384 * 768 * 2);

  // 1) fused conversions
  cvt_all_kernel<<<9368, 256, 0, stream>>>(x, x_bf, W_in, W_out, W_x, WinT, WoutT, WxT);
  // 2) GEMM1: 256x256 8-phase, grid = (16384/256)*(1536/256) = 64*6 = 384
  gemm_8x<0, 512><<<384, 512, 0, stream>>>(x_bf, WinT, xssm, siluz, 6, 1536);
  // 3) u = xssm @ W_x
  u_kernel<<<4096, 256, 0, stream>>>(xssm, WxT, u);
  // 4-6) chunked scan
  scan_phase1<<<1536, 256, 0, stream>>>(xssm, u, W_dt, b_dt, A_log, Sws, Hws);
  scan_phase2<<<192, 256, 0, stream>>>(Sws, Hws, A_log, Hin);
  scan_phase3<<<1536, 256, 0, stream>>>(xssm, u, W_dt, b_dt, A_log, D_par, siluz, Hin, yz);
  // 7) GEMM2 (r11-proven): BM=128, grid = 128*4 = 512
  gemm_sb<1, 128, 768><<<512, 256, 0, stream>>>(yz, WoutT, out, nullptr, 4, 512);
}

// Round 17
// 138.384 us; speedup vs baseline: 1.0980x; 1.0980x over previous
//
#include <hip/hip_runtime.h>

typedef unsigned short bfu;
typedef __attribute__((ext_vector_type(8))) short short8;
typedef __attribute__((ext_vector_type(4))) float f32x4;

__device__ __forceinline__ float bf2f(bfu u){
  union { unsigned int i; float f; } v; v.i = ((unsigned int)u) << 16; return v.f;
}
__device__ __forceinline__ bfu f2bf(float f){
  union { float f; unsigned int i; } v; v.f = f;
  unsigned int r = (v.i + 0x7FFFu + ((v.i >> 16) & 1u)) >> 16;
  return (bfu)r;
}
__device__ __forceinline__ float fexp2(float x){ return __builtin_amdgcn_exp2f(x); }
__device__ __forceinline__ float flog2(float x){ return __builtin_amdgcn_logf(x); }
__device__ __forceinline__ float softplusf(float x){
  float t = fexp2(-fabsf(x) * 1.44269504088896f);
  return fmaxf(x, 0.f) + 0.69314718055995f * flog2(1.f + t);
}
__device__ __forceinline__ void gload16(const bfu* g, bfu* l){
  __builtin_amdgcn_global_load_lds((const __attribute__((address_space(1))) unsigned int*)g,
                                   (__attribute__((address_space(3))) unsigned int*)l, 16, 0, 0);
}

// ---------------- fused conversion kernel (LDS-tiled coalesced transposes) ----------------
// blocks 0..8191            : x (f32) -> x_bf (coalesced float4)
// blocks 8192..8959 (768)   : W_in 512x1536 -> WinT 1536x512 bf16, 32x32 LDS tiles
// blocks 8960..9343 (384)   : W_out 768x512 -> WoutT 512x768 bf16, 32x32 LDS tiles
// blocks 9344..9367 (24)    : W_x 768x8 -> WxT 8x768 f32 (tiny)
__global__ __launch_bounds__(256) void cvt_all_kernel(const float* __restrict__ x, bfu* __restrict__ x_bf,
                                                      const float* __restrict__ W_in, const float* __restrict__ W_out,
                                                      const float* __restrict__ W_x,
                                                      bfu* __restrict__ WinT, bfu* __restrict__ WoutT,
                                                      float* __restrict__ WxT){
  __shared__ float T[32][33];
  const int bid = blockIdx.x;
  const int tid = threadIdx.x;
  if (bid < 8192){
    int g = bid * 256 + tid;
    float4 v = ((const float4*)x)[g];
    ushort4 o;
    o.x = f2bf(v.x); o.y = f2bf(v.y); o.z = f2bf(v.z); o.w = f2bf(v.w);
    ((ushort4*)x_bf)[g] = o;
    return;
  }
  const int lr = tid >> 3;         // 0..31
  const int lc = tid & 7;          // 0..7 (x4 floats)
  if (bid < 8960){
    int ti = bid - 8192;
    int r0 = (ti & 15) * 32, c0 = (ti >> 4) * 32;
    float4 v = *(const float4*)(W_in + (size_t)(r0 + lr) * 1536 + c0 + lc * 4);
    T[lr][lc * 4 + 0] = v.x; T[lr][lc * 4 + 1] = v.y;
    T[lr][lc * 4 + 2] = v.z; T[lr][lc * 4 + 3] = v.w;
    __syncthreads();
    ushort4 o;
    o.x = f2bf(T[lc * 4 + 0][lr]); o.y = f2bf(T[lc * 4 + 1][lr]);
    o.z = f2bf(T[lc * 4 + 2][lr]); o.w = f2bf(T[lc * 4 + 3][lr]);
    *(ushort4*)(WinT + (size_t)(c0 + lr) * 512 + r0 + lc * 4) = o;
  } else if (bid < 9344){
    int ti = bid - 8960;
    int r0 = (ti % 24) * 32, c0 = (ti / 24) * 32;
    float4 v = *(const float4*)(W_out + (size_t)(r0 + lr) * 512 + c0 + lc * 4);
    T[lr][lc * 4 + 0] = v.x; T[lr][lc * 4 + 1] = v.y;
    T[lr][lc * 4 + 2] = v.z; T[lr][lc * 4 + 3] = v.w;
    __syncthreads();
    ushort4 o;
    o.x = f2bf(T[lc * 4 + 0][lr]); o.y = f2bf(T[lc * 4 + 1][lr]);
    o.z = f2bf(T[lc * 4 + 2][lr]); o.w = f2bf(T[lc * 4 + 3][lr]);
    *(ushort4*)(WoutT + (size_t)(c0 + lr) * 768 + r0 + lc * 4) = o;
  } else {
    int h = (bid - 9344) * 256 + tid;    // 0..6143
    int n = h / 768, k = h % 768;
    WxT[h] = W_x[(size_t)k * 8 + n];
  }
}

// ---------------- MFMA GEMM (r11-proven): BM x 128, BK=64, single-buffer ----------------
// Nine schedule/geometry variants (r4-r16) bracket this structure: it is the
// practical ceiling for these shapes at 2+ blocks/CU.  Do not re-pipeline.
template<int EPI, int BM, int KK>
__global__ __launch_bounds__(BM * 2)
void gemm_sb(const bfu* __restrict__ Amat, const bfu* __restrict__ Bt,
             void* __restrict__ out0, void* __restrict__ out1,
             int NBN, int N)
{
  constexpr int BN = 128;
  constexpr int THREADS = BM * 2;
  constexpr int RPI = THREADS / 8;
  __shared__ bfu As[BM * 64];
  __shared__ bfu Bs[BN * 64];
  const int tid  = threadIdx.x;
  const int lane = tid & 63;
  const int w    = tid >> 6;
  const int wr   = w >> 1, wc = w & 1;

  const int cpx = gridDim.x >> 3;
  const int id  = blockIdx.x;
  const int nid = (id & 7) * cpx + (id >> 3);
  const int bn  = nid % NBN;
  const int bm  = nid / NBN;

  const int srow = tid >> 3;
  const int scol = ((tid & 7) ^ (srow & 7)) * 8;
  const bfu* gA = Amat + ((size_t)(bm * BM + srow)) * KK + scol;
  const bfu* gB = Bt   + ((size_t)(bn * BN + srow)) * KK + scol;
  bfu* lA = As + srow * 64 + (tid & 7) * 8;
  bfu* lB = Bs + srow * 64 + (tid & 7) * 8;

  f32x4 acc[4][4];
  #pragma unroll
  for (int i = 0; i < 4; i++)
    #pragma unroll
    for (int j = 0; j < 4; j++)
      #pragma unroll
      for (int r = 0; r < 4; r++) acc[i][j][r] = 0.f;

  for (int k0 = 0; k0 < KK; k0 += 64){
    #pragma unroll
    for (int i = 0; i < BM / RPI; i++)
      gload16(gA + (size_t)(i * RPI) * KK + k0, lA + i * RPI * 64);
    #pragma unroll
    for (int j = 0; j < BN / RPI; j++)
      gload16(gB + (size_t)(j * RPI) * KK + k0, lB + j * RPI * 64);
    __syncthreads();

    #pragma unroll
    for (int kk = 0; kk < 2; kk++){
      short8 a[4], b[4];
      const int sA = ((kk * 4 + (lane >> 4)) ^ (lane & 7)) * 8;
      #pragma unroll
      for (int m = 0; m < 4; m++){
        int r = wr * 64 + m * 16 + (lane & 15);
        a[m] = *(const short8*)&As[r * 64 + sA];
      }
      #pragma unroll
      for (int n = 0; n < 4; n++){
        int r = wc * 64 + n * 16 + (lane & 15);
        b[n] = *(const short8*)&Bs[r * 64 + sA];
      }
      #pragma unroll
      for (int m = 0; m < 4; m++)
        #pragma unroll
        for (int n = 0; n < 4; n++)
          acc[m][n] = __builtin_amdgcn_mfma_f32_16x16x32_bf16(a[m], b[n], acc[m][n], 0, 0, 0);
    }
    __syncthreads();
  }

  #pragma unroll
  for (int m = 0; m < 4; m++){
    #pragma unroll
    for (int n = 0; n < 4; n++){
      const int row0 = bm * BM + wr * 64 + m * 16 + (lane >> 4) * 4;
      const int col  = bn * BN + wc * 64 + n * 16 + (lane & 15);
      #pragma unroll
      for (int r = 0; r < 4; r++){
        float v = acc[m][n][r];
        int row = row0 + r;
        if (EPI == 0){
          float s = v / (1.f + __expf(-v));   // silu
          if (col < 768) ((bfu*)out0)[(size_t)row * 768 + col]         = f2bf(s);
          else           ((bfu*)out1)[(size_t)row * 768 + (col - 768)] = f2bf(s);
        } else {
          ((float*)out0)[(size_t)row * N + col] = v;
        }
      }
    }
  }
}

// ---------------- u = xssm @ W_x  (uses WxT [8][768], coalesced) ----------------
__global__ __launch_bounds__(256) void u_kernel(const bfu* __restrict__ xssm, const float* __restrict__ WxT,
                                                float* __restrict__ u){
  int wid = threadIdx.x >> 6, lane = threadIdx.x & 63;
  int row = blockIdx.x * 4 + wid;
  const bfu* xr = xssm + (size_t)row * 768;
  float acc[8];
  #pragma unroll
  for (int n = 0; n < 8; n++) acc[n] = 0.f;
  #pragma unroll
  for (int i = 0; i < 3; i++){
    int kb = i * 256 + lane * 4;
    ushort4 xq = *(const ushort4*)(xr + kb);
    float x0 = bf2f(xq.x), x1 = bf2f(xq.y), x2 = bf2f(xq.z), x3 = bf2f(xq.w);
    #pragma unroll
    for (int n = 0; n < 8; n++){
      float4 wv = *(const float4*)(WxT + (size_t)n * 768 + kb);
      acc[n] += x0 * wv.x + x1 * wv.y + x2 * wv.z + x3 * wv.w;
    }
  }
  #pragma unroll
  for (int n = 0; n < 8; n++){
    #pragma unroll
    for (int off = 32; off >= 1; off >>= 1) acc[n] += __shfl_xor(acc[n], off, 64);
  }
  if (lane == 0){
    float4 o0 = { acc[0], acc[1], acc[2], acc[3] };
    float4 o1 = { acc[4], acc[5], acc[6], acc[7] };
    *(float4*)(u + (size_t)row * 8)     = o0;
    *(float4*)(u + (size_t)row * 8 + 4) = o1;
  }
}

// ---------------- scan phase 1: 1 d/thread, u staged in LDS, delta inline ----------------
__global__ __launch_bounds__(256) void scan_phase1(const bfu* __restrict__ xssm, const float* __restrict__ u,
    const float* __restrict__ Wdt, const float* __restrict__ bdt, const float* __restrict__ A_log,
    float* __restrict__ Sws, float* __restrict__ Hws){
  __shared__ float uS[32][8];
  int tid = threadIdx.x;
  int bid = blockIdx.x;
  int b = bid / 192; int rem = bid % 192;
  int c = rem / 3;   int dblk = rem % 3;
  int d = dblk * 256 + tid;
  int r0 = b * 2048 + c * 32;
  uS[tid >> 3][tid & 7] = u[(size_t)(r0 + (tid >> 3)) * 8 + (tid & 7)];
  float Al2[8], H[8], Wr[8];
  float bd = bdt[d], S = 0.f;
  #pragma unroll
  for (int n = 0; n < 8; n++){
    Al2[n] = -__expf(A_log[(size_t)d * 8 + n]) * 1.4426950408889634f;
    Wr[n]  = Wdt[(size_t)n * 768 + d];
    H[n] = 0.f;
  }
  __syncthreads();
  size_t base = (size_t)r0 * 768 + d;
  #pragma unroll 8
  for (int i = 0; i < 32; i++){
    float4 u0 = *(const float4*)&uS[i][0];
    float4 u1 = *(const float4*)&uS[i][4];
    float xt = bf2f(xssm[base + (size_t)i * 768]);
    float dv = bd + u0.x * Wr[0] + u0.y * Wr[1] + u0.z * Wr[2] + u0.w * Wr[3]
                  + u1.x * Wr[4] + u1.y * Wr[5] + u1.z * Wr[6] + u1.w * Wr[7];
    float dt = softplusf(dv);
    float dx = dt * xt;
    S += dt;
    #pragma unroll
    for (int n = 0; n < 8; n++){
      float e = fexp2(dt * Al2[n]);
      H[n] = e * H[n] + dx;
    }
  }
  size_t o = (((size_t)b * 64 + c) * 768 + d) * 8;
  float4 h0 = { H[0], H[1], H[2], H[3] };
  float4 h1 = { H[4], H[5], H[6], H[7] };
  *(float4*)(Hws + o)     = h0;
  *(float4*)(Hws + o + 4) = h1;
  Sws[((size_t)b * 64 + c) * 768 + d] = S;
}

// ---------------- scan phase 2: combine chunks (P derived from S), batched prefetch ----------------
__global__ __launch_bounds__(256) void scan_phase2(const float* __restrict__ Sws, const float* __restrict__ Hws,
                                                   const float* __restrict__ A_log, float* __restrict__ Hin){
  int g = blockIdx.x * 256 + threadIdx.x;   // 49152 = 8*768*8
  int within = g % 6144;                    // d*8+n
  int b = g / 6144;
  int d = within >> 3, n = within & 7;
  float Al2 = -__expf(A_log[(size_t)d * 8 + n]) * 1.4426950408889634f;
  size_t baseH = (size_t)b * 64 * 6144 + within;
  size_t baseS = (size_t)b * 64 * 768 + d;
  float hin = 0.f;
  float sv[16], hv[16];
  #pragma unroll
  for (int B = 0; B < 4; B++){
    #pragma unroll
    for (int i = 0; i < 16; i++){
      sv[i] = Sws[baseS + (size_t)(B * 16 + i) * 768];
      hv[i] = Hws[baseH + (size_t)(B * 16 + i) * 6144];
    }
    #pragma unroll
    for (int i = 0; i < 16; i++){
      size_t idx = baseH + (size_t)(B * 16 + i) * 6144;
      Hin[idx] = hin;
      hin = fexp2(sv[i] * Al2) * hin + hv[i];
    }
  }
}

// ---------------- scan phase 3: 1 d/thread, u staged in LDS, gate fused ----------------
__global__ __launch_bounds__(256) void scan_phase3(const bfu* __restrict__ xssm, const float* __restrict__ u,
    const float* __restrict__ Wdt, const float* __restrict__ bdt, const float* __restrict__ A_log,
    const float* __restrict__ Dp, const bfu* __restrict__ siluz, const float* __restrict__ Hin,
    bfu* __restrict__ yz){
  __shared__ float uS[32][8];
  int tid = threadIdx.x;
  int bid = blockIdx.x;
  int b = bid / 192; int rem = bid % 192;
  int c = rem / 3;   int dblk = rem % 3;
  int d = dblk * 256 + tid;
  int r0 = b * 2048 + c * 32;
  uS[tid >> 3][tid & 7] = u[(size_t)(r0 + (tid >> 3)) * 8 + (tid & 7)];
  float Al2[8], H[8], Wr[8];
  float bd = bdt[d], Dd = Dp[d];
  size_t o = (((size_t)b * 64 + c) * 768 + d) * 8;
  float4 h0 = *(const float4*)(Hin + o);
  float4 h1 = *(const float4*)(Hin + o + 4);
  H[0] = h0.x; H[1] = h0.y; H[2] = h0.z; H[3] = h0.w;
  H[4] = h1.x; H[5] = h1.y; H[6] = h1.z; H[7] = h1.w;
  #pragma unroll
  for (int n = 0; n < 8; n++){
    Al2[n] = -__expf(A_log[(size_t)d * 8 + n]) * 1.4426950408889634f;
    Wr[n]  = Wdt[(size_t)n * 768 + d];
  }
  __syncthreads();
  size_t base = (size_t)r0 * 768 + d;
  #pragma unroll 8
  for (int i = 0; i < 32; i++){
    float4 u0 = *(const float4*)&uS[i][0];
    float4 u1 = *(const float4*)&uS[i][4];
    float xt = bf2f(xssm[base + (size_t)i * 768]);
    float sz = bf2f(siluz[base + (size_t)i * 768]);
    float dv = bd + u0.x * Wr[0] + u0.y * Wr[1] + u0.z * Wr[2] + u0.w * Wr[3]
                  + u1.x * Wr[4] + u1.y * Wr[5] + u1.z * Wr[6] + u1.w * Wr[7];
    float dt = softplusf(dv);
    float dx = dt * xt;
    float y = Dd * xt;
    #pragma unroll
    for (int n = 0; n < 8; n++){
      float e = fexp2(dt * Al2[n]);
      H[n] = e * H[n] + dx;
      y += H[n];
    }
    yz[base + (size_t)i * 768] = f2bf(y * sz);
  }
}

extern "C" void kernel_launch(void* const* d_in, const int* in_sizes, int n_in,
                              void* d_out, int out_size, void* d_ws, size_t ws_size,
                              hipStream_t stream){
  const float* x     = (const float*)d_in[0];
  const float* W_in  = (const float*)d_in[1];
  const float* A_log = (const float*)d_in[2];
  const float* D_par = (const float*)d_in[3];
  const float* W_x   = (const float*)d_in[4];
  const float* W_dt  = (const float*)d_in[5];
  const float* b_dt  = (const float*)d_in[6];
  const float* W_out = (const float*)d_in[7];
  float* out = (float*)d_out;
  (void)in_sizes; (void)n_in; (void)out_size; (void)ws_size;

  char* base = (char*)d_ws;
  size_t off = 0;
  auto alloc = [&](size_t bytes)->char*{
    char* p = base + off; off += (bytes + 255) & ~(size_t)255; return p;
  };
  bfu*   x_bf  = (bfu*)  alloc((size_t)16384 * 512 * 2);
  bfu*   WinT  = (bfu*)  alloc((size_t)1536 * 512 * 2);
  bfu*   WoutT = (bfu*)  alloc((size_t)512 * 768 * 2);
  float* WxT   = (float*)alloc((size_t)8 * 768 * 4);
  bfu*   xssm  = (bfu*)  alloc((size_t)16384 * 768 * 2);
  bfu*   siluz = (bfu*)  alloc((size_t)16384 * 768 * 2);
  float* u     = (float*)alloc((size_t)16384 * 8 * 4);
  float* Sws   = (float*)alloc((size_t)8 * 64 * 768 * 4);
  float* Hws   = (float*)alloc((size_t)8 * 64 * 768 * 8 * 4);
  float* Hin   = (float*)alloc((size_t)8 * 64 * 768 * 8 * 4);
  bfu*   yz    = (bfu*)  alloc((size_t)16384 * 768 * 2);

  // 1) fused conversions (LDS-tiled coalesced weight transposes)
  cvt_all_kernel<<<9368, 256, 0, stream>>>(x, x_bf, W_in, W_out, W_x, WinT, WoutT, WxT);
  // 2) GEMM1 (r11/r15-proven best): BM=256, grid = 64*12 = 768
  gemm_sb<0, 256, 512><<<768, 512, 0, stream>>>(x_bf, WinT, xssm, siluz, 12, 1536);
  // 3) u = xssm @ W_x
  u_kernel<<<4096, 256, 0, stream>>>(xssm, WxT, u);
  // 4-6) chunked scan (1 d/thread, u in LDS, S-factorized workspace)
  scan_phase1<<<1536, 256, 0, stream>>>(xssm, u, W_dt, b_dt, A_log, Sws, Hws);
  scan_phase2<<<192, 256, 0, stream>>>(Sws, Hws, A_log, Hin);
  scan_phase3<<<1536, 256, 0, stream>>>(xssm, u, W_dt, b_dt, A_log, D_par, siluz, Hin, yz);
  // 7) GEMM2 (r11-proven): BM=128, grid = 128*4 = 512
  gemm_sb<1, 128, 768><<<512, 256, 0, stream>>>(yz, WoutT, out, nullptr, 4, 512);
}